// Round 1
// baseline (4183.047 us; speedup 1.0000x reference)
//
#include <hip/hip_runtime.h>

#define HEADS 4
#define EPS 1e-16f

// ---- monotonic float<->uint mapping for atomicMax on signed floats ----
__device__ inline unsigned fordr(float f) {
    unsigned u = __float_as_uint(f);
    return (u & 0x80000000u) ? ~u : (u | 0x80000000u);
}
__device__ inline float funordr(unsigned m) {
    return (m & 0x80000000u) ? __uint_as_float(m & 0x7FFFFFFFu)
                             : __uint_as_float(~m);
}

// ================= conv1: fused QKVS projection (128 -> 4x32) =============
// qkvs layout per node: [0:32)=q, [32:64)=k, [64:96)=v, [96:128)=s
__global__ __launch_bounds__(256) void proj1_kernel(
    const float* __restrict__ x,
    const float* __restrict__ Wq, const float* __restrict__ bq,
    const float* __restrict__ Wk, const float* __restrict__ bk,
    const float* __restrict__ Wv, const float* __restrict__ bv,
    const float* __restrict__ Ws, const float* __restrict__ bs,
    float* __restrict__ qkvs, int n)
{
    __shared__ float Wl[128][128];
    __shared__ float bl[128];
    __shared__ float xl[2][128];
    for (int i = threadIdx.x; i < 128 * 128; i += 256) {
        int k = i >> 7, col = i & 127;
        int sub = col >> 5, j = col & 31;
        const float* W = (sub == 0) ? Wq : (sub == 1) ? Wk : (sub == 2) ? Wv : Ws;
        Wl[k][col] = W[k * 32 + j];
    }
    if (threadIdx.x < 128) {
        int col = threadIdx.x, sub = col >> 5, j = col & 31;
        const float* b = (sub == 0) ? bq : (sub == 1) ? bk : (sub == 2) ? bv : bs;
        bl[col] = b[j];
    }
    __syncthreads();
    int r = threadIdx.x >> 7;        // 0..1
    int col = threadIdx.x & 127;
    for (int row0 = blockIdx.x * 2; row0 < n; row0 += gridDim.x * 2) {
        int li = threadIdx.x;
        int rr = row0 + (li >> 7);
        if (rr < n) xl[li >> 7][li & 127] = x[(size_t)rr * 128 + (li & 127)];
        __syncthreads();
        int row = row0 + r;
        if (row < n) {
            float acc = bl[col];
            #pragma unroll
            for (int k = 0; k < 128; ++k) acc += xl[r][k] * Wl[k][col];
            qkvs[(size_t)row * 128 + col] = acc;
        }
        __syncthreads();
    }
}

// ================= conv2 projection (32 -> 4x16) ==========================
// qkvs2 layout per node: [0:16)=q, [16:32)=k, [32:48)=v, [48:64)=s
__global__ __launch_bounds__(256) void proj2_kernel(
    const float* __restrict__ h1,
    const float* __restrict__ Wq, const float* __restrict__ bq,
    const float* __restrict__ Wk, const float* __restrict__ bk,
    const float* __restrict__ Wv, const float* __restrict__ bv,
    const float* __restrict__ Ws, const float* __restrict__ bs,
    float* __restrict__ qkvs2, int n)
{
    __shared__ float Wl[32][64];
    __shared__ float bl[64];
    __shared__ float xl[4][32];
    for (int i = threadIdx.x; i < 32 * 64; i += 256) {
        int k = i >> 6, col = i & 63;
        int sub = col >> 4, j = col & 15;
        const float* W = (sub == 0) ? Wq : (sub == 1) ? Wk : (sub == 2) ? Wv : Ws;
        Wl[k][col] = W[k * 16 + j];
    }
    if (threadIdx.x < 64) {
        int col = threadIdx.x, sub = col >> 4, j = col & 15;
        const float* b = (sub == 0) ? bq : (sub == 1) ? bk : (sub == 2) ? bv : bs;
        bl[col] = b[j];
    }
    __syncthreads();
    int r = threadIdx.x >> 6, col = threadIdx.x & 63;
    for (int row0 = blockIdx.x * 4; row0 < n; row0 += gridDim.x * 4) {
        int li = threadIdx.x;
        if (li < 128) {
            int rr = row0 + (li >> 5);
            if (rr < n) xl[li >> 5][li & 31] = h1[(size_t)rr * 32 + (li & 31)];
        }
        __syncthreads();
        int row = row0 + r;
        if (row < n) {
            float acc = bl[col];
            #pragma unroll
            for (int k = 0; k < 32; ++k) acc += xl[r][k] * Wl[k][col];
            qkvs2[(size_t)row * 64 + col] = acc;
        }
        __syncthreads();
    }
}

// ================= edge pass 1: attention logits + segment max ============
__global__ __launch_bounds__(256) void edge_alpha1(
    const int* __restrict__ ei, int E, const float* __restrict__ qkvs,
    float* __restrict__ alpha, unsigned* __restrict__ amax)
{
    int tid = blockIdx.x * 256 + threadIdx.x;
    if (tid >= E * HEADS) return;
    int e = tid >> 2, h = tid & 3;
    int src = ei[e], dst = ei[E + e];
    const float4* qp = (const float4*)(qkvs + (size_t)dst * 128 + h * 8);
    const float4* kp = (const float4*)(qkvs + (size_t)src * 128 + 32 + h * 8);
    float4 q0 = qp[0], q1 = qp[1], k0 = kp[0], k1 = kp[1];
    float d = q0.x * k0.x + q0.y * k0.y + q0.z * k0.z + q0.w * k0.w
            + q1.x * k1.x + q1.y * k1.y + q1.z * k1.z + q1.w * k1.w;
    float a = d * 0.35355339059327373f;  // 1/sqrt(8)
    alpha[tid] = a;
    atomicMax(amax + dst * 4 + h, fordr(a));
}

__global__ __launch_bounds__(256) void edge_alpha2(
    const int* __restrict__ ei, int E, const float* __restrict__ qkvs2,
    float* __restrict__ alpha, unsigned* __restrict__ amax)
{
    int tid = blockIdx.x * 256 + threadIdx.x;
    if (tid >= E * HEADS) return;
    int e = tid >> 2, h = tid & 3;
    int src = ei[e], dst = ei[E + e];
    float4 q = *(const float4*)(qkvs2 + (size_t)dst * 64 + h * 4);
    float4 k = *(const float4*)(qkvs2 + (size_t)src * 64 + 16 + h * 4);
    float a = (q.x * k.x + q.y * k.y + q.z * k.z + q.w * k.w) * 0.5f; // 1/sqrt(4)
    alpha[tid] = a;
    atomicMax(amax + dst * 4 + h, fordr(a));
}

// ========== edge pass 2: exp, denom, unnormalized numerator ===============
__global__ __launch_bounds__(256) void edge_msg1(
    const int* __restrict__ ei, int E, const float* __restrict__ qkvs,
    const float* __restrict__ alpha, const unsigned* __restrict__ amax,
    float* __restrict__ denom, float* __restrict__ numer)
{
    int tid = blockIdx.x * 256 + threadIdx.x;
    if (tid >= E * HEADS) return;
    int e = tid >> 2, h = tid & 3;
    int src = ei[e], dst = ei[E + e];
    float m = funordr(amax[dst * 4 + h]);
    float ea = __expf(alpha[tid] - m);
    atomicAdd(denom + dst * 4 + h, ea);
    const float4* vp = (const float4*)(qkvs + (size_t)src * 128 + 64 + h * 8);
    float4 v0 = vp[0], v1 = vp[1];
    float* np = numer + (size_t)dst * 32 + h * 8;
    atomicAdd(np + 0, ea * v0.x); atomicAdd(np + 1, ea * v0.y);
    atomicAdd(np + 2, ea * v0.z); atomicAdd(np + 3, ea * v0.w);
    atomicAdd(np + 4, ea * v1.x); atomicAdd(np + 5, ea * v1.y);
    atomicAdd(np + 6, ea * v1.z); atomicAdd(np + 7, ea * v1.w);
}

__global__ __launch_bounds__(256) void edge_msg2(
    const int* __restrict__ ei, int E, const float* __restrict__ qkvs2,
    const float* __restrict__ alpha, const unsigned* __restrict__ amax,
    float* __restrict__ denom, float* __restrict__ numer2)
{
    int tid = blockIdx.x * 256 + threadIdx.x;
    if (tid >= E * HEADS) return;
    int e = tid >> 2, h = tid & 3;
    int src = ei[e], dst = ei[E + e];
    float m = funordr(amax[dst * 4 + h]);
    float ea = __expf(alpha[tid] - m);
    atomicAdd(denom + dst * 4 + h, ea);
    float4 v = *(const float4*)(qkvs2 + (size_t)src * 64 + 32 + h * 4);
    float* np = numer2 + (size_t)dst * 16 + h * 4;
    atomicAdd(np + 0, ea * v.x); atomicAdd(np + 1, ea * v.y);
    atomicAdd(np + 2, ea * v.z); atomicAdd(np + 3, ea * v.w);
}

// ================= finalize conv1: normalize + skip + relu ================
__global__ __launch_bounds__(256) void finalize1(
    const float* __restrict__ numer, const float* __restrict__ denom,
    const float* __restrict__ qkvs, float* __restrict__ h1, int n)
{
    int tid = blockIdx.x * 256 + threadIdx.x;
    if (tid >= n * 32) return;
    int node = tid >> 5, j = tid & 31, h = j >> 3;
    float val = numer[tid] / (denom[node * 4 + h] + EPS)
              + qkvs[(size_t)node * 128 + 96 + j];
    h1[tid] = fmaxf(val, 0.f);
}

// ====== finalize conv2 + mean-pool accumulation (block-local reduce) ======
__global__ __launch_bounds__(256) void finalize2_pool(
    const float* __restrict__ numer2, const float* __restrict__ denom,
    const float* __restrict__ qkvs2, const int* __restrict__ batch,
    float* __restrict__ pooled, float* __restrict__ cnt, int n)
{
    __shared__ float acc[16];
    __shared__ int bShared;
    __shared__ int uniform;
    int node0 = blockIdx.x * 16;
    int t = threadIdx.x;
    int node = node0 + (t >> 4), j = t & 15, h = j >> 2;
    if (t == 0) {
        int bFirst = batch[node0];
        int bLast = batch[min(node0 + 15, n - 1)];
        bShared = bFirst;
        uniform = (bFirst == bLast);
    }
    if (t < 16) acc[t] = 0.f;
    __syncthreads();
    bool active = node < n;
    float val = 0.f;
    if (active) {
        val = numer2[(size_t)node * 16 + j] / (denom[node * 4 + h] + EPS)
            + qkvs2[(size_t)node * 64 + 48 + j];
        val = fmaxf(val, 0.f);
    }
    if (uniform) {
        if (active) atomicAdd(&acc[j], val);
        __syncthreads();
        int nlocal = min(16, n - node0);
        if (t < 16) atomicAdd(pooled + bShared * 16 + t, acc[t]);
        if (t == 0) atomicAdd(cnt + bShared, (float)nlocal);
    } else {
        if (active) {
            int b = batch[node];
            atomicAdd(pooled + b * 16 + j, val);
            if (j == 0) atomicAdd(cnt + b, 1.f);
        }
    }
}

// ================= final FC on pooled [64,16] -> [64,10] ==================
__global__ void fc_kernel(
    const float* __restrict__ pooled, const float* __restrict__ cnt,
    const float* __restrict__ Wfc, const float* __restrict__ bfc,
    float* __restrict__ out)
{
    int t = threadIdx.x;
    if (t < 64 * 10) {
        int b = t / 10, o = t % 10;
        float c = fmaxf(cnt[b], 1.0f);
        float acc = bfc[o];
        #pragma unroll
        for (int k = 0; k < 16; ++k)
            acc += (pooled[b * 16 + k] / c) * Wfc[k * 10 + o];
        out[t] = acc;
    }
}

extern "C" void kernel_launch(void* const* d_in, const int* in_sizes, int n_in,
                              void* d_out, int out_size, void* d_ws, size_t ws_size,
                              hipStream_t stream) {
    const float* x     = (const float*)d_in[0];
    const int*   ei    = (const int*)d_in[1];
    const int*   batch = (const int*)d_in[2];
    const float* Wq1 = (const float*)d_in[3],  *bq1 = (const float*)d_in[4];
    const float* Wk1 = (const float*)d_in[5],  *bk1 = (const float*)d_in[6];
    const float* Wv1 = (const float*)d_in[7],  *bv1 = (const float*)d_in[8];
    const float* Ws1 = (const float*)d_in[9],  *bs1 = (const float*)d_in[10];
    const float* Wq2 = (const float*)d_in[11], *bq2 = (const float*)d_in[12];
    const float* Wk2 = (const float*)d_in[13], *bk2 = (const float*)d_in[14];
    const float* Wv2 = (const float*)d_in[15], *bv2 = (const float*)d_in[16];
    const float* Ws2 = (const float*)d_in[17], *bs2 = (const float*)d_in[18];
    const float* Wfc = (const float*)d_in[19], *bfc = (const float*)d_in[20];

    int N = in_sizes[0] / 128;
    int E = in_sizes[1] / 2;

    float* ws = (float*)d_ws;
    float* qkvs1  = ws;                                   // N*128 floats (conv2 reuses as qkvs2: N*64)
    float* alpha  = qkvs1 + (size_t)N * 128;              // E*4
    float* amaxF  = alpha + (size_t)E * 4;                // N*4
    float* denom  = amaxF + (size_t)N * 4;                // N*4
    float* numer  = denom + (size_t)N * 4;                // N*32 (conv2 reuses: N*16)
    float* pooled = numer + (size_t)N * 32;               // 64*16
    float* cnt    = pooled + 64 * 16;                     // 64
    float* h1     = cnt + 64;                             // N*32
    unsigned* amaxU = (unsigned*)amaxF;

    // zero amax, denom, numer, pooled, cnt (every call: harness doesn't re-poison)
    hipMemsetAsync(amaxF, 0,
                   ((size_t)N * 4 + (size_t)N * 4 + (size_t)N * 32 + 64 * 16 + 64) * 4,
                   stream);

    int egrid = (E * HEADS + 255) / 256;

    // ---- conv1 ----
    proj1_kernel<<<1024, 256, 0, stream>>>(x, Wq1, bq1, Wk1, bk1, Wv1, bv1, Ws1, bs1, qkvs1, N);
    edge_alpha1<<<egrid, 256, 0, stream>>>(ei, E, qkvs1, alpha, amaxU);
    edge_msg1<<<egrid, 256, 0, stream>>>(ei, E, qkvs1, alpha, amaxU, denom, numer);
    finalize1<<<((size_t)N * 32 + 255) / 256, 256, 0, stream>>>(numer, denom, qkvs1, h1, N);

    // re-zero segment buffers for conv2
    hipMemsetAsync(amaxF, 0, ((size_t)N * 4 + (size_t)N * 4 + (size_t)N * 32) * 4, stream);

    // ---- conv2 (qkvs2 reuses qkvs1 region; numer2 reuses numer) ----
    proj2_kernel<<<1024, 256, 0, stream>>>(h1, Wq2, bq2, Wk2, bk2, Wv2, bv2, Ws2, bs2, qkvs1, N);
    edge_alpha2<<<egrid, 256, 0, stream>>>(ei, E, qkvs1, alpha, amaxU);
    edge_msg2<<<egrid, 256, 0, stream>>>(ei, E, qkvs1, alpha, amaxU, denom, numer);
    finalize2_pool<<<(N + 15) / 16, 256, 0, stream>>>(numer, denom, qkvs1, batch, pooled, cnt, N);
    fc_kernel<<<1, 640, 0, stream>>>(pooled, cnt, Wfc, bfc, (float*)d_out);
}

// Round 2
// 1186.995 us; speedup vs baseline: 3.5241x; 3.5241x over previous
//
#include <hip/hip_runtime.h>

#define HEADS 4
#define EPS 1e-16f

// ================= conv1: fused QKVS projection (128 -> 4x32) =============
// qkvs layout per node: [0:32)=q, [32:64)=k, [64:96)=v, [96:128)=s
__global__ __launch_bounds__(256) void proj1_kernel(
    const float* __restrict__ x,
    const float* __restrict__ Wq, const float* __restrict__ bq,
    const float* __restrict__ Wk, const float* __restrict__ bk,
    const float* __restrict__ Wv, const float* __restrict__ bv,
    const float* __restrict__ Ws, const float* __restrict__ bs,
    float* __restrict__ qkvs, int n)
{
    __shared__ float Wl[128][128];
    __shared__ float bl[128];
    __shared__ float xl[2][128];
    for (int i = threadIdx.x; i < 128 * 128; i += 256) {
        int k = i >> 7, col = i & 127;
        int sub = col >> 5, j = col & 31;
        const float* W = (sub == 0) ? Wq : (sub == 1) ? Wk : (sub == 2) ? Wv : Ws;
        Wl[k][col] = W[k * 32 + j];
    }
    if (threadIdx.x < 128) {
        int col = threadIdx.x, sub = col >> 5, j = col & 31;
        const float* b = (sub == 0) ? bq : (sub == 1) ? bk : (sub == 2) ? bv : bs;
        bl[col] = b[j];
    }
    __syncthreads();
    int r = threadIdx.x >> 7;        // 0..1
    int col = threadIdx.x & 127;
    for (int row0 = blockIdx.x * 2; row0 < n; row0 += gridDim.x * 2) {
        int li = threadIdx.x;
        int rr = row0 + (li >> 7);
        if (rr < n) xl[li >> 7][li & 127] = x[(size_t)rr * 128 + (li & 127)];
        __syncthreads();
        int row = row0 + r;
        if (row < n) {
            float acc = bl[col];
            #pragma unroll
            for (int k = 0; k < 128; ++k) acc += xl[r][k] * Wl[k][col];
            qkvs[(size_t)row * 128 + col] = acc;
        }
        __syncthreads();
    }
}

// ================= conv2 projection (32 -> 4x16) ==========================
// qkvs2 layout per node: [0:16)=q, [16:32)=k, [32:48)=v, [48:64)=s
__global__ __launch_bounds__(256) void proj2_kernel(
    const float* __restrict__ h1,
    const float* __restrict__ Wq, const float* __restrict__ bq,
    const float* __restrict__ Wk, const float* __restrict__ bk,
    const float* __restrict__ Wv, const float* __restrict__ bv,
    const float* __restrict__ Ws, const float* __restrict__ bs,
    float* __restrict__ qkvs2, int n)
{
    __shared__ float Wl[32][64];
    __shared__ float bl[64];
    __shared__ float xl[4][32];
    for (int i = threadIdx.x; i < 32 * 64; i += 256) {
        int k = i >> 6, col = i & 63;
        int sub = col >> 4, j = col & 15;
        const float* W = (sub == 0) ? Wq : (sub == 1) ? Wk : (sub == 2) ? Wv : Ws;
        Wl[k][col] = W[k * 16 + j];
    }
    if (threadIdx.x < 64) {
        int col = threadIdx.x, sub = col >> 4, j = col & 15;
        const float* b = (sub == 0) ? bq : (sub == 1) ? bk : (sub == 2) ? bv : bs;
        bl[col] = b[j];
    }
    __syncthreads();
    int r = threadIdx.x >> 6, col = threadIdx.x & 63;
    for (int row0 = blockIdx.x * 4; row0 < n; row0 += gridDim.x * 4) {
        int li = threadIdx.x;
        if (li < 128) {
            int rr = row0 + (li >> 5);
            if (rr < n) xl[li >> 5][li & 31] = h1[(size_t)rr * 32 + (li & 31)];
        }
        __syncthreads();
        int row = row0 + r;
        if (row < n) {
            float acc = bl[col];
            #pragma unroll
            for (int k = 0; k < 32; ++k) acc += xl[r][k] * Wl[k][col];
            qkvs2[(size_t)row * 64 + col] = acc;
        }
        __syncthreads();
    }
}

// ================= CSR build: degree histogram ============================
__global__ __launch_bounds__(256) void degree_kernel(
    const int* __restrict__ ei, int E, int* __restrict__ deg)
{
    int e = blockIdx.x * 256 + threadIdx.x;
    if (e >= E) return;
    atomicAdd(deg + ei[E + e], 1);
}

// ============ one-block exclusive scan over deg -> row_ptr, woff ==========
__global__ __launch_bounds__(1024) void scan_kernel(
    const int* __restrict__ deg, int* __restrict__ row_ptr,
    int* __restrict__ woff, int n)
{
    __shared__ int part[1024];
    int t = threadIdx.x;
    int chunk = (n + 1023) / 1024;
    int lo = t * chunk, hi = min(lo + chunk, n);
    int s = 0;
    for (int i = lo; i < hi; ++i) s += deg[i];
    part[t] = s;
    __syncthreads();
    for (int off = 1; off < 1024; off <<= 1) {
        int add = (t >= off) ? part[t - off] : 0;
        __syncthreads();
        part[t] += add;
        __syncthreads();
    }
    int prefix = (t == 0) ? 0 : part[t - 1];
    for (int i = lo; i < hi; ++i) {
        row_ptr[i] = prefix;
        woff[i] = prefix;
        prefix += deg[i];
    }
}

// ================= CSR build: scatter src into col ========================
__global__ __launch_bounds__(256) void scatter_kernel(
    const int* __restrict__ ei, int E, int* __restrict__ woff,
    int* __restrict__ col)
{
    int e = blockIdx.x * 256 + threadIdx.x;
    if (e >= E) return;
    int src = ei[e], dst = ei[E + e];
    int pos = atomicAdd(woff + dst, 1);
    col[pos] = src;
}

// ===== conv1 fused gather: online softmax over incoming edges, no atomics =
// thread = (node, head); q in regs; k/v gathered; +skip +relu
__global__ __launch_bounds__(256) void gather_conv1(
    const int* __restrict__ row_ptr, const int* __restrict__ deg,
    const int* __restrict__ col, const float* __restrict__ qkvs,
    float* __restrict__ h1, int n)
{
    int tid = blockIdx.x * 256 + threadIdx.x;
    if (tid >= n * HEADS) return;
    int node = tid >> 2, h = tid & 3;
    const float4* qp = (const float4*)(qkvs + (size_t)node * 128 + h * 8);
    float4 q0 = qp[0], q1 = qp[1];
    int start = row_ptr[node], d = deg[node];
    float m = -INFINITY, s = 0.f;
    float a0x=0,a0y=0,a0z=0,a0w=0,a1x=0,a1y=0,a1z=0,a1w=0;
    for (int i = 0; i < d; ++i) {
        int src = col[start + i];
        const float4* kp = (const float4*)(qkvs + (size_t)src * 128 + 32 + h * 8);
        float4 k0 = kp[0], k1 = kp[1];
        float a = (q0.x*k0.x + q0.y*k0.y + q0.z*k0.z + q0.w*k0.w
                 + q1.x*k1.x + q1.y*k1.y + q1.z*k1.z + q1.w*k1.w)
                * 0.35355339059327373f;  // 1/sqrt(8)
        float mn = fmaxf(m, a);
        float corr = __expf(m - mn);   // first iter: exp(-inf)=0
        float ea = __expf(a - mn);
        s = s * corr + ea;
        const float4* vp = (const float4*)(qkvs + (size_t)src * 128 + 64 + h * 8);
        float4 v0 = vp[0], v1 = vp[1];
        a0x = a0x*corr + ea*v0.x; a0y = a0y*corr + ea*v0.y;
        a0z = a0z*corr + ea*v0.z; a0w = a0w*corr + ea*v0.w;
        a1x = a1x*corr + ea*v1.x; a1y = a1y*corr + ea*v1.y;
        a1z = a1z*corr + ea*v1.z; a1w = a1w*corr + ea*v1.w;
        m = mn;
    }
    float inv = 1.f / (s + EPS);
    const float* sk = qkvs + (size_t)node * 128 + 96 + h * 8;
    float4 o0, o1;
    o0.x = fmaxf(a0x*inv + sk[0], 0.f); o0.y = fmaxf(a0y*inv + sk[1], 0.f);
    o0.z = fmaxf(a0z*inv + sk[2], 0.f); o0.w = fmaxf(a0w*inv + sk[3], 0.f);
    o1.x = fmaxf(a1x*inv + sk[4], 0.f); o1.y = fmaxf(a1y*inv + sk[5], 0.f);
    o1.z = fmaxf(a1z*inv + sk[6], 0.f); o1.w = fmaxf(a1w*inv + sk[7], 0.f);
    float4* op = (float4*)(h1 + (size_t)node * 32 + h * 8);
    op[0] = o0; op[1] = o1;
}

// ===== conv2 fused gather (C=4) + skip + relu -> h2[N][16] ================
__global__ __launch_bounds__(256) void gather_conv2(
    const int* __restrict__ row_ptr, const int* __restrict__ deg,
    const int* __restrict__ col, const float* __restrict__ qkvs2,
    float* __restrict__ h2, int n)
{
    int tid = blockIdx.x * 256 + threadIdx.x;
    if (tid >= n * HEADS) return;
    int node = tid >> 2, h = tid & 3;
    float4 q = *(const float4*)(qkvs2 + (size_t)node * 64 + h * 4);
    int start = row_ptr[node], d = deg[node];
    float m = -INFINITY, s = 0.f;
    float ax=0, ay=0, az=0, aw=0;
    for (int i = 0; i < d; ++i) {
        int src = col[start + i];
        float4 k = *(const float4*)(qkvs2 + (size_t)src * 64 + 16 + h * 4);
        float a = (q.x*k.x + q.y*k.y + q.z*k.z + q.w*k.w) * 0.5f; // 1/sqrt(4)
        float mn = fmaxf(m, a);
        float corr = __expf(m - mn);
        float ea = __expf(a - mn);
        s = s * corr + ea;
        float4 v = *(const float4*)(qkvs2 + (size_t)src * 64 + 32 + h * 4);
        ax = ax*corr + ea*v.x; ay = ay*corr + ea*v.y;
        az = az*corr + ea*v.z; aw = aw*corr + ea*v.w;
        m = mn;
    }
    float inv = 1.f / (s + EPS);
    const float* sk = qkvs2 + (size_t)node * 64 + 48 + h * 4;
    float4 o;
    o.x = fmaxf(ax*inv + sk[0], 0.f);
    o.y = fmaxf(ay*inv + sk[1], 0.f);
    o.z = fmaxf(az*inv + sk[2], 0.f);
    o.w = fmaxf(aw*inv + sk[3], 0.f);
    *(float4*)(h2 + (size_t)node * 16 + h * 4) = o;
}

// ====== mean-pool accumulation over h2 (block-local reduce, batch sorted) =
__global__ __launch_bounds__(256) void pool_kernel(
    const float* __restrict__ h2, const int* __restrict__ batch,
    float* __restrict__ pooled, float* __restrict__ cnt, int n)
{
    __shared__ float acc[16];
    __shared__ int bShared;
    __shared__ int uniform;
    int node0 = blockIdx.x * 16;
    int t = threadIdx.x;
    int node = node0 + (t >> 4), j = t & 15;
    if (t == 0) {
        int bFirst = batch[node0];
        int bLast = batch[min(node0 + 15, n - 1)];
        bShared = bFirst;
        uniform = (bFirst == bLast);
    }
    if (t < 16) acc[t] = 0.f;
    __syncthreads();
    bool active = node < n;
    float val = active ? h2[(size_t)node * 16 + j] : 0.f;
    if (uniform) {
        if (active) atomicAdd(&acc[j], val);
        __syncthreads();
        int nlocal = min(16, n - node0);
        if (t < 16) atomicAdd(pooled + bShared * 16 + t, acc[t]);
        if (t == 0) atomicAdd(cnt + bShared, (float)nlocal);
    } else {
        if (active) {
            int b = batch[node];
            atomicAdd(pooled + b * 16 + j, val);
            if (j == 0) atomicAdd(cnt + b, 1.f);
        }
    }
}

// ================= final FC on pooled [64,16] -> [64,10] ==================
__global__ void fc_kernel(
    const float* __restrict__ pooled, const float* __restrict__ cnt,
    const float* __restrict__ Wfc, const float* __restrict__ bfc,
    float* __restrict__ out)
{
    int t = threadIdx.x;
    if (t < 64 * 10) {
        int b = t / 10, o = t % 10;
        float c = fmaxf(cnt[b], 1.0f);
        float acc = bfc[o];
        #pragma unroll
        for (int k = 0; k < 16; ++k)
            acc += (pooled[b * 16 + k] / c) * Wfc[k * 10 + o];
        out[t] = acc;
    }
}

extern "C" void kernel_launch(void* const* d_in, const int* in_sizes, int n_in,
                              void* d_out, int out_size, void* d_ws, size_t ws_size,
                              hipStream_t stream) {
    const float* x     = (const float*)d_in[0];
    const int*   ei    = (const int*)d_in[1];
    const int*   batch = (const int*)d_in[2];
    const float* Wq1 = (const float*)d_in[3],  *bq1 = (const float*)d_in[4];
    const float* Wk1 = (const float*)d_in[5],  *bk1 = (const float*)d_in[6];
    const float* Wv1 = (const float*)d_in[7],  *bv1 = (const float*)d_in[8];
    const float* Ws1 = (const float*)d_in[9],  *bs1 = (const float*)d_in[10];
    const float* Wq2 = (const float*)d_in[11], *bq2 = (const float*)d_in[12];
    const float* Wk2 = (const float*)d_in[13], *bk2 = (const float*)d_in[14];
    const float* Wv2 = (const float*)d_in[15], *bv2 = (const float*)d_in[16];
    const float* Ws2 = (const float*)d_in[17], *bs2 = (const float*)d_in[18];
    const float* Wfc = (const float*)d_in[19], *bfc = (const float*)d_in[20];

    int N = in_sizes[0] / 128;
    int E = in_sizes[1] / 2;

    // ---- workspace layout ----
    float* ws = (float*)d_ws;
    float* qkvs1  = ws;                                   // N*128 f (conv2 reuses as qkvs2: N*64)
    float* h1     = qkvs1 + (size_t)N * 128;              // N*32 f
    float* h2     = h1 + (size_t)N * 32;                  // N*16 f
    float* pooled = h2 + (size_t)N * 16;                  // 64*16 f
    float* cnt    = pooled + 64 * 16;                     // 64 f
    int* deg     = (int*)(cnt + 64);                      // N ints
    int* row_ptr = deg + N;                               // N ints
    int* woff    = row_ptr + N;                           // N ints
    int* col     = woff + N;                              // E ints

    // zero: deg (histogram) + pooled + cnt (accumulators). every call.
    hipMemsetAsync(deg, 0, (size_t)N * sizeof(int), stream);
    hipMemsetAsync(pooled, 0, (64 * 16 + 64) * sizeof(float), stream);

    int egrid = (E + 255) / 256;
    int ngrid = (N * HEADS + 255) / 256;

    // ---- CSR build (shared by both convs) ----
    degree_kernel<<<egrid, 256, 0, stream>>>(ei, E, deg);
    scan_kernel<<<1, 1024, 0, stream>>>(deg, row_ptr, woff, N);
    scatter_kernel<<<egrid, 256, 0, stream>>>(ei, E, woff, col);

    // ---- conv1 ----
    proj1_kernel<<<1024, 256, 0, stream>>>(x, Wq1, bq1, Wk1, bk1, Wv1, bv1, Ws1, bs1, qkvs1, N);
    gather_conv1<<<ngrid, 256, 0, stream>>>(row_ptr, deg, col, qkvs1, h1, N);

    // ---- conv2 (qkvs2 reuses qkvs1 region) ----
    proj2_kernel<<<1024, 256, 0, stream>>>(h1, Wq2, bq2, Wk2, bk2, Wv2, bv2, Ws2, bs2, qkvs1, N);
    gather_conv2<<<ngrid, 256, 0, stream>>>(row_ptr, deg, col, qkvs1, h2, N);

    // ---- pool + fc ----
    pool_kernel<<<(N + 15) / 16, 256, 0, stream>>>(h2, batch, pooled, cnt, N);
    fc_kernel<<<1, 640, 0, stream>>>(pooled, cnt, Wfc, bfc, (float*)d_out);
}

// Round 3
// 862.511 us; speedup vs baseline: 4.8498x; 1.3762x over previous
//
#include <hip/hip_runtime.h>

#define HEADS 4
#define EPS 1e-16f

// ========== CSR pass 1: degree histogram + per-edge rank (atomic return) ==
__global__ __launch_bounds__(256) void degree_rank_kernel(
    const int* __restrict__ ei, int E, int* __restrict__ deg,
    int* __restrict__ rank)
{
    int base = (blockIdx.x * 256 + threadIdx.x) * 4;
    if (base + 3 < E) {
        int4 d = *(const int4*)(ei + E + base);
        int r0 = atomicAdd(deg + d.x, 1);
        int r1 = atomicAdd(deg + d.y, 1);
        int r2 = atomicAdd(deg + d.z, 1);
        int r3 = atomicAdd(deg + d.w, 1);
        *(int4*)(rank + base) = make_int4(r0, r1, r2, r3);
    } else {
        for (int e = base; e < E; ++e)
            rank[e] = atomicAdd(deg + ei[E + e], 1);
    }
}

// ============ CSR pass 2: one-block exclusive scan over deg ==============
__global__ __launch_bounds__(1024) void scan_kernel(
    const int* __restrict__ deg, int* __restrict__ row_ptr, int n)
{
    __shared__ int part[1024];
    int t = threadIdx.x;
    int chunk = (n + 1023) / 1024;
    int lo = t * chunk, hi = min(lo + chunk, n);
    int s = 0;
    for (int i = lo; i < hi; ++i) s += deg[i];
    part[t] = s;
    __syncthreads();
    for (int off = 1; off < 1024; off <<= 1) {
        int add = (t >= off) ? part[t - off] : 0;
        __syncthreads();
        part[t] += add;
        __syncthreads();
    }
    int prefix = (t == 0) ? 0 : part[t - 1];
    for (int i = lo; i < hi; ++i) {
        row_ptr[i] = prefix;
        prefix += deg[i];
    }
}

// ==== CSR pass 3: XCD-partitioned fill, no atomics, write-local col =======
// blockIdx%8 = partition = XCD (bid%8 round-robin on MI355X). Each partition
// scans the full dst array but writes ONLY its own contiguous col slice, so
// every col cache line is produced by a single XCD's L2 (full-line
// accumulation instead of cross-XCD false sharing).
__global__ __launch_bounds__(256) void fill_kernel(
    const int* __restrict__ ei, const int* __restrict__ rank,
    const int* __restrict__ row_ptr, int E, int n, int* __restrict__ col)
{
    int part = blockIdx.x & 7;
    int g = blockIdx.x >> 3;
    int nb = gridDim.x >> 3;
    int lo = (int)(((long long)n * part) >> 3);
    int hi = (int)(((long long)n * (part + 1)) >> 3);
    int stride = nb * 256 * 4;
    for (int base = (g * 256 + threadIdx.x) * 4; base < E; base += stride) {
        if (base + 3 < E) {
            int4 d = *(const int4*)(ei + E + base);
            if (d.x >= lo && d.x < hi) col[row_ptr[d.x] + rank[base + 0]] = ei[base + 0];
            if (d.y >= lo && d.y < hi) col[row_ptr[d.y] + rank[base + 1]] = ei[base + 1];
            if (d.z >= lo && d.z < hi) col[row_ptr[d.z] + rank[base + 2]] = ei[base + 2];
            if (d.w >= lo && d.w < hi) col[row_ptr[d.w] + rank[base + 3]] = ei[base + 3];
        } else {
            for (int e = base; e < E; ++e) {
                int dv = ei[E + e];
                if (dv >= lo && dv < hi) col[row_ptr[dv] + rank[e]] = ei[e];
            }
        }
    }
}

// ================= conv1: fused QKVS projection (128 -> 4x32) =============
// qkvs layout per node: [0:32)=q, [32:64)=k, [64:96)=v, [96:128)=s
// 8 rows staged per iter; each thread computes 4 rows x 1 col.
__global__ __launch_bounds__(256) void proj1_kernel(
    const float* __restrict__ x,
    const float* __restrict__ Wq, const float* __restrict__ bq,
    const float* __restrict__ Wk, const float* __restrict__ bk,
    const float* __restrict__ Wv, const float* __restrict__ bv,
    const float* __restrict__ Ws, const float* __restrict__ bs,
    float* __restrict__ qkvs, int n)
{
    __shared__ float Wl[128][128];
    __shared__ float bl[128];
    __shared__ float xl[8][128];
    for (int i = threadIdx.x; i < 128 * 128; i += 256) {
        int k = i >> 7, c = i & 127;
        int sub = c >> 5, j = c & 31;
        const float* W = (sub == 0) ? Wq : (sub == 1) ? Wk : (sub == 2) ? Wv : Ws;
        Wl[k][c] = W[k * 32 + j];
    }
    if (threadIdx.x < 128) {
        int c = threadIdx.x, sub = c >> 5, j = c & 31;
        const float* b = (sub == 0) ? bq : (sub == 1) ? bk : (sub == 2) ? bv : bs;
        bl[c] = b[j];
    }
    __syncthreads();
    int col = threadIdx.x & 127;
    int rb = (threadIdx.x >> 7) * 4;    // 0 or 4
    for (int row0 = blockIdx.x * 8; row0 < n; row0 += gridDim.x * 8) {
        int t = threadIdx.x;
        int r = t >> 5, c4 = (t & 31) * 4;
        int gr = row0 + r;
        float4 xv = (gr < n) ? *(const float4*)(x + (size_t)gr * 128 + c4)
                             : make_float4(0.f, 0.f, 0.f, 0.f);
        *(float4*)(&xl[r][c4]) = xv;
        __syncthreads();
        float acc0 = bl[col], acc1 = bl[col], acc2 = bl[col], acc3 = bl[col];
        #pragma unroll 4
        for (int k = 0; k < 128; ++k) {
            float w = Wl[k][col];
            acc0 += xl[rb + 0][k] * w;
            acc1 += xl[rb + 1][k] * w;
            acc2 += xl[rb + 2][k] * w;
            acc3 += xl[rb + 3][k] * w;
        }
        if (row0 + rb + 0 < n) qkvs[(size_t)(row0 + rb + 0) * 128 + col] = acc0;
        if (row0 + rb + 1 < n) qkvs[(size_t)(row0 + rb + 1) * 128 + col] = acc1;
        if (row0 + rb + 2 < n) qkvs[(size_t)(row0 + rb + 2) * 128 + col] = acc2;
        if (row0 + rb + 3 < n) qkvs[(size_t)(row0 + rb + 3) * 128 + col] = acc3;
        __syncthreads();
    }
}

// ================= conv2 projection (32 -> 4x16) ==========================
// qkvs2 layout per node: [0:16)=q, [16:32)=k, [32:48)=v, [48:64)=s
__global__ __launch_bounds__(256) void proj2_kernel(
    const float* __restrict__ h1,
    const float* __restrict__ Wq, const float* __restrict__ bq,
    const float* __restrict__ Wk, const float* __restrict__ bk,
    const float* __restrict__ Wv, const float* __restrict__ bv,
    const float* __restrict__ Ws, const float* __restrict__ bs,
    float* __restrict__ qkvs2, int n)
{
    __shared__ float Wl[32][64];
    __shared__ float bl[64];
    __shared__ float xl[4][32];
    for (int i = threadIdx.x; i < 32 * 64; i += 256) {
        int k = i >> 6, c = i & 63;
        int sub = c >> 4, j = c & 15;
        const float* W = (sub == 0) ? Wq : (sub == 1) ? Wk : (sub == 2) ? Wv : Ws;
        Wl[k][c] = W[k * 16 + j];
    }
    if (threadIdx.x < 64) {
        int c = threadIdx.x, sub = c >> 4, j = c & 15;
        const float* b = (sub == 0) ? bq : (sub == 1) ? bk : (sub == 2) ? bv : bs;
        bl[c] = b[j];
    }
    __syncthreads();
    int r = threadIdx.x >> 6, col = threadIdx.x & 63;
    for (int row0 = blockIdx.x * 4; row0 < n; row0 += gridDim.x * 4) {
        int li = threadIdx.x;
        if (li < 128) {
            int rr = row0 + (li >> 5);
            if (rr < n) xl[li >> 5][li & 31] = h1[(size_t)rr * 32 + (li & 31)];
        }
        __syncthreads();
        int row = row0 + r;
        if (row < n) {
            float acc = bl[col];
            #pragma unroll
            for (int k = 0; k < 32; ++k) acc += xl[r][k] * Wl[k][col];
            qkvs2[(size_t)row * 64 + col] = acc;
        }
        __syncthreads();
    }
}

// ===== conv1 fused gather: online softmax over incoming edges, no atomics =
__global__ __launch_bounds__(256) void gather_conv1(
    const int* __restrict__ row_ptr, const int* __restrict__ deg,
    const int* __restrict__ col, const float* __restrict__ qkvs,
    float* __restrict__ h1, int n)
{
    int tid = blockIdx.x * 256 + threadIdx.x;
    if (tid >= n * HEADS) return;
    int node = tid >> 2, h = tid & 3;
    const float4* qp = (const float4*)(qkvs + (size_t)node * 128 + h * 8);
    float4 q0 = qp[0], q1 = qp[1];
    int start = row_ptr[node], d = deg[node];
    float m = -INFINITY, s = 0.f;
    float a0x=0,a0y=0,a0z=0,a0w=0,a1x=0,a1y=0,a1z=0,a1w=0;
    for (int i = 0; i < d; ++i) {
        int src = col[start + i];
        const float4* kp = (const float4*)(qkvs + (size_t)src * 128 + 32 + h * 8);
        float4 k0 = kp[0], k1 = kp[1];
        float a = (q0.x*k0.x + q0.y*k0.y + q0.z*k0.z + q0.w*k0.w
                 + q1.x*k1.x + q1.y*k1.y + q1.z*k1.z + q1.w*k1.w)
                * 0.35355339059327373f;  // 1/sqrt(8)
        float mn = fmaxf(m, a);
        float corr = __expf(m - mn);   // first iter: exp(-inf)=0
        float ea = __expf(a - mn);
        s = s * corr + ea;
        const float4* vp = (const float4*)(qkvs + (size_t)src * 128 + 64 + h * 8);
        float4 v0 = vp[0], v1 = vp[1];
        a0x = a0x*corr + ea*v0.x; a0y = a0y*corr + ea*v0.y;
        a0z = a0z*corr + ea*v0.z; a0w = a0w*corr + ea*v0.w;
        a1x = a1x*corr + ea*v1.x; a1y = a1y*corr + ea*v1.y;
        a1z = a1z*corr + ea*v1.z; a1w = a1w*corr + ea*v1.w;
        m = mn;
    }
    float inv = 1.f / (s + EPS);
    const float* sk = qkvs + (size_t)node * 128 + 96 + h * 8;
    float4 o0, o1;
    o0.x = fmaxf(a0x*inv + sk[0], 0.f); o0.y = fmaxf(a0y*inv + sk[1], 0.f);
    o0.z = fmaxf(a0z*inv + sk[2], 0.f); o0.w = fmaxf(a0w*inv + sk[3], 0.f);
    o1.x = fmaxf(a1x*inv + sk[4], 0.f); o1.y = fmaxf(a1y*inv + sk[5], 0.f);
    o1.z = fmaxf(a1z*inv + sk[6], 0.f); o1.w = fmaxf(a1w*inv + sk[7], 0.f);
    float4* op = (float4*)(h1 + (size_t)node * 32 + h * 8);
    op[0] = o0; op[1] = o1;
}

// ===== conv2 fused gather (C=4) + skip + relu -> h2[N][16] ================
__global__ __launch_bounds__(256) void gather_conv2(
    const int* __restrict__ row_ptr, const int* __restrict__ deg,
    const int* __restrict__ col, const float* __restrict__ qkvs2,
    float* __restrict__ h2, int n)
{
    int tid = blockIdx.x * 256 + threadIdx.x;
    if (tid >= n * HEADS) return;
    int node = tid >> 2, h = tid & 3;
    float4 q = *(const float4*)(qkvs2 + (size_t)node * 64 + h * 4);
    int start = row_ptr[node], d = deg[node];
    float m = -INFINITY, s = 0.f;
    float ax=0, ay=0, az=0, aw=0;
    for (int i = 0; i < d; ++i) {
        int src = col[start + i];
        float4 k = *(const float4*)(qkvs2 + (size_t)src * 64 + 16 + h * 4);
        float a = (q.x*k.x + q.y*k.y + q.z*k.z + q.w*k.w) * 0.5f; // 1/sqrt(4)
        float mn = fmaxf(m, a);
        float corr = __expf(m - mn);
        float ea = __expf(a - mn);
        s = s * corr + ea;
        float4 v = *(const float4*)(qkvs2 + (size_t)src * 64 + 32 + h * 4);
        ax = ax*corr + ea*v.x; ay = ay*corr + ea*v.y;
        az = az*corr + ea*v.z; aw = aw*corr + ea*v.w;
        m = mn;
    }
    float inv = 1.f / (s + EPS);
    const float* sk = qkvs2 + (size_t)node * 64 + 48 + h * 4;
    float4 o;
    o.x = fmaxf(ax*inv + sk[0], 0.f);
    o.y = fmaxf(ay*inv + sk[1], 0.f);
    o.z = fmaxf(az*inv + sk[2], 0.f);
    o.w = fmaxf(aw*inv + sk[3], 0.f);
    *(float4*)(h2 + (size_t)node * 16 + h * 4) = o;
}

// ====== mean-pool accumulation over h2 (block-local reduce, batch sorted) =
__global__ __launch_bounds__(256) void pool_kernel(
    const float* __restrict__ h2, const int* __restrict__ batch,
    float* __restrict__ pooled, float* __restrict__ cnt, int n)
{
    __shared__ float acc[16];
    __shared__ int bShared;
    __shared__ int uniform;
    int node0 = blockIdx.x * 16;
    int t = threadIdx.x;
    int node = node0 + (t >> 4), j = t & 15;
    if (t == 0) {
        int bFirst = batch[node0];
        int bLast = batch[min(node0 + 15, n - 1)];
        bShared = bFirst;
        uniform = (bFirst == bLast);
    }
    if (t < 16) acc[t] = 0.f;
    __syncthreads();
    bool active = node < n;
    float val = active ? h2[(size_t)node * 16 + j] : 0.f;
    if (uniform) {
        if (active) atomicAdd(&acc[j], val);
        __syncthreads();
        int nlocal = min(16, n - node0);
        if (t < 16) atomicAdd(pooled + bShared * 16 + t, acc[t]);
        if (t == 0) atomicAdd(cnt + bShared, (float)nlocal);
    } else {
        if (active) {
            int b = batch[node];
            atomicAdd(pooled + b * 16 + j, val);
            if (j == 0) atomicAdd(cnt + b, 1.f);
        }
    }
}

// ================= final FC on pooled [64,16] -> [64,10] ==================
__global__ void fc_kernel(
    const float* __restrict__ pooled, const float* __restrict__ cnt,
    const float* __restrict__ Wfc, const float* __restrict__ bfc,
    float* __restrict__ out)
{
    int t = threadIdx.x;
    if (t < 64 * 10) {
        int b = t / 10, o = t % 10;
        float c = fmaxf(cnt[b], 1.0f);
        float acc = bfc[o];
        #pragma unroll
        for (int k = 0; k < 16; ++k)
            acc += (pooled[b * 16 + k] / c) * Wfc[k * 10 + o];
        out[t] = acc;
    }
}

extern "C" void kernel_launch(void* const* d_in, const int* in_sizes, int n_in,
                              void* d_out, int out_size, void* d_ws, size_t ws_size,
                              hipStream_t stream) {
    const float* x     = (const float*)d_in[0];
    const int*   ei    = (const int*)d_in[1];
    const int*   batch = (const int*)d_in[2];
    const float* Wq1 = (const float*)d_in[3],  *bq1 = (const float*)d_in[4];
    const float* Wk1 = (const float*)d_in[5],  *bk1 = (const float*)d_in[6];
    const float* Wv1 = (const float*)d_in[7],  *bv1 = (const float*)d_in[8];
    const float* Ws1 = (const float*)d_in[9],  *bs1 = (const float*)d_in[10];
    const float* Wq2 = (const float*)d_in[11], *bq2 = (const float*)d_in[12];
    const float* Wk2 = (const float*)d_in[13], *bk2 = (const float*)d_in[14];
    const float* Wv2 = (const float*)d_in[15], *bv2 = (const float*)d_in[16];
    const float* Ws2 = (const float*)d_in[17], *bs2 = (const float*)d_in[18];
    const float* Wfc = (const float*)d_in[19], *bfc = (const float*)d_in[20];

    int N = in_sizes[0] / 128;
    int E = in_sizes[1] / 2;

    // ---- workspace layout ----
    float* ws = (float*)d_ws;
    float* qkvs1  = ws;                                   // N*128 f (conv2 reuses as qkvs2: N*64)
    float* h1     = qkvs1 + (size_t)N * 128;              // N*32 f (aliased as rank[] during CSR build)
    float* h2     = h1 + (size_t)N * 32;                  // N*16 f
    float* pooled = h2 + (size_t)N * 16;                  // 64*16 f
    float* cnt    = pooled + 64 * 16;                     // 64 f
    int* deg     = (int*)(cnt + 64);                      // N ints
    int* row_ptr = deg + N;                               // N ints
    int* col     = row_ptr + N;                           // E ints
    int* rank    = (int*)h1;                              // E ints, dead after fill_kernel

    // zero: deg (histogram) + pooled + cnt (accumulators). every call.
    hipMemsetAsync(deg, 0, (size_t)N * sizeof(int), stream);
    hipMemsetAsync(pooled, 0, (64 * 16 + 64) * sizeof(float), stream);

    int ngrid = (N * HEADS + 255) / 256;

    // ---- CSR build (shared by both convs) ----
    degree_rank_kernel<<<(E + 1023) / 1024, 256, 0, stream>>>(ei, E, deg, rank);
    scan_kernel<<<1, 1024, 0, stream>>>(deg, row_ptr, N);
    fill_kernel<<<2048, 256, 0, stream>>>(ei, rank, row_ptr, E, N, col);

    // ---- conv1 ----
    proj1_kernel<<<1024, 256, 0, stream>>>(x, Wq1, bq1, Wk1, bk1, Wv1, bv1, Ws1, bs1, qkvs1, N);
    gather_conv1<<<ngrid, 256, 0, stream>>>(row_ptr, deg, col, qkvs1, h1, N);

    // ---- conv2 (qkvs2 reuses qkvs1 region) ----
    proj2_kernel<<<1024, 256, 0, stream>>>(h1, Wq2, bq2, Wk2, bk2, Wv2, bv2, Ws2, bs2, qkvs1, N);
    gather_conv2<<<ngrid, 256, 0, stream>>>(row_ptr, deg, col, qkvs1, h2, N);

    // ---- pool + fc ----
    pool_kernel<<<(N + 15) / 16, 256, 0, stream>>>(h2, batch, pooled, cnt, N);
    fc_kernel<<<1, 640, 0, stream>>>(pooled, cnt, Wfc, bfc, (float*)d_out);
}

// Round 4
// 674.845 us; speedup vs baseline: 6.1985x; 1.2781x over previous
//
#include <hip/hip_runtime.h>

#define HEADS 4
#define EPS 1e-16f
#define SB 256   // scan blocks

// ========== CSR pass 1: degree histogram + per-edge rank (atomic return) ==
__global__ __launch_bounds__(256) void degree_rank_kernel(
    const int* __restrict__ ei, int E, int* __restrict__ deg,
    int* __restrict__ rank)
{
    int base = (blockIdx.x * 256 + threadIdx.x) * 4;
    if (base + 3 < E) {
        int4 d = *(const int4*)(ei + E + base);
        int r0 = atomicAdd(deg + d.x, 1);
        int r1 = atomicAdd(deg + d.y, 1);
        int r2 = atomicAdd(deg + d.z, 1);
        int r3 = atomicAdd(deg + d.w, 1);
        *(int4*)(rank + base) = make_int4(r0, r1, r2, r3);
    } else {
        for (int e = base; e < E; ++e)
            rank[e] = atomicAdd(deg + ei[E + e], 1);
    }
}

// ============ CSR pass 2a: per-block partial sums of deg ==================
__global__ __launch_bounds__(256) void scan_partial(
    const int* __restrict__ deg, int* __restrict__ bsum, int n)
{
    __shared__ int red[256];
    int chunk = (n + SB - 1) / SB;
    int lo = blockIdx.x * chunk;
    int hi = min(lo + chunk, n);
    int s = 0;
    for (int i = lo + threadIdx.x; i < hi; i += 256) s += deg[i];
    red[threadIdx.x] = s;
    __syncthreads();
    for (int off = 128; off > 0; off >>= 1) {
        if (threadIdx.x < off) red[threadIdx.x] += red[threadIdx.x + off];
        __syncthreads();
    }
    if (threadIdx.x == 0) bsum[blockIdx.x] = red[0];
}

// ============ CSR pass 2b: exclusive scan of the 256 block sums ===========
__global__ __launch_bounds__(256) void scan_bsums(int* __restrict__ bsum)
{
    __shared__ int tmp[256];
    int t = threadIdx.x;
    tmp[t] = bsum[t];
    __syncthreads();
    for (int off = 1; off < 256; off <<= 1) {
        int add = (t >= off) ? tmp[t - off] : 0;
        __syncthreads();
        tmp[t] += add;
        __syncthreads();
    }
    bsum[t] = (t == 0) ? 0 : tmp[t - 1];
}

// ============ CSR pass 2c: per-block exclusive scan -> row_ptr ============
__global__ __launch_bounds__(256) void scan_write(
    const int* __restrict__ deg, const int* __restrict__ bsum,
    int* __restrict__ row_ptr, int n)
{
    __shared__ int tmp[256];
    int chunk = (n + SB - 1) / SB;
    int lo = blockIdx.x * chunk;
    int hi = min(lo + chunk, n);
    int k = (chunk + 255) / 256;
    int tlo = lo + threadIdx.x * k;
    int thi = min(tlo + k, hi);
    int s = 0;
    for (int i = tlo; i < thi; ++i) s += deg[i];
    tmp[threadIdx.x] = s;
    __syncthreads();
    for (int off = 1; off < 256; off <<= 1) {
        int add = (threadIdx.x >= off) ? tmp[threadIdx.x - off] : 0;
        __syncthreads();
        tmp[threadIdx.x] += add;
        __syncthreads();
    }
    int prefix = bsum[blockIdx.x] + ((threadIdx.x == 0) ? 0 : tmp[threadIdx.x - 1]);
    for (int i = tlo; i < thi; ++i) {
        row_ptr[i] = prefix;
        prefix += deg[i];
    }
}

// ==== CSR pass 3: XCD-partitioned fill, no atomics, write-local col =======
__global__ __launch_bounds__(256) void fill_kernel(
    const int* __restrict__ ei, const int* __restrict__ rank,
    const int* __restrict__ row_ptr, int E, int n, int* __restrict__ col)
{
    int part = blockIdx.x & 7;
    int g = blockIdx.x >> 3;
    int nb = gridDim.x >> 3;
    int lo = (int)(((long long)n * part) >> 3);
    int hi = (int)(((long long)n * (part + 1)) >> 3);
    int stride = nb * 256 * 4;
    for (int base = (g * 256 + threadIdx.x) * 4; base < E; base += stride) {
        if (base + 3 < E) {
            int4 d = *(const int4*)(ei + E + base);
            if (d.x >= lo && d.x < hi) col[row_ptr[d.x] + rank[base + 0]] = ei[base + 0];
            if (d.y >= lo && d.y < hi) col[row_ptr[d.y] + rank[base + 1]] = ei[base + 1];
            if (d.z >= lo && d.z < hi) col[row_ptr[d.z] + rank[base + 2]] = ei[base + 2];
            if (d.w >= lo && d.w < hi) col[row_ptr[d.w] + rank[base + 3]] = ei[base + 3];
        } else {
            for (int e = base; e < E; ++e) {
                int dv = ei[E + e];
                if (dv >= lo && dv < hi) col[row_ptr[dv] + rank[e]] = ei[e];
            }
        }
    }
}

// ================= conv1: fused QKVS projection (128 -> 4x32) =============
// qkvs layout per node: [0:32)=q, [32:64)=k, [64:96)=v, [96:128)=s
// 8 rows/iter; thread = 1 row x 4 cols; Wl read as float4 (ds_read_b128).
__global__ __launch_bounds__(256) void proj1_kernel(
    const float* __restrict__ x,
    const float* __restrict__ Wq, const float* __restrict__ bq,
    const float* __restrict__ Wk, const float* __restrict__ bk,
    const float* __restrict__ Wv, const float* __restrict__ bv,
    const float* __restrict__ Ws, const float* __restrict__ bs,
    float* __restrict__ qkvs, int n)
{
    __shared__ float Wl[128][128];
    __shared__ float xl[8][128];
    for (int i = threadIdx.x; i < 128 * 128; i += 256) {
        int k = i >> 7, c = i & 127;
        int sub = c >> 5, j = c & 31;
        const float* W = (sub == 0) ? Wq : (sub == 1) ? Wk : (sub == 2) ? Wv : Ws;
        Wl[k][c] = W[k * 32 + j];
    }
    int col4 = (threadIdx.x & 31) * 4;
    float4 bias4;
    {
        int sub = col4 >> 5, j = col4 & 31;
        const float* b = (sub == 0) ? bq : (sub == 1) ? bk : (sub == 2) ? bv : bs;
        bias4 = *(const float4*)(b + j);
    }
    __syncthreads();
    int row_in = threadIdx.x >> 5;   // 0..7
    for (int row0 = blockIdx.x * 8; row0 < n; row0 += gridDim.x * 8) {
        // stage 8 rows = 256 float4s, one per thread, fully coalesced
        int f4 = threadIdx.x;
        int gr = row0 + (f4 >> 5);
        float4 xv = (gr < n) ? *(const float4*)(x + (size_t)gr * 128 + (f4 & 31) * 4)
                             : make_float4(0.f, 0.f, 0.f, 0.f);
        *(float4*)(&xl[f4 >> 5][(f4 & 31) * 4]) = xv;
        __syncthreads();
        float4 acc = bias4;
        #pragma unroll 8
        for (int k = 0; k < 128; ++k) {
            float xr = xl[row_in][k];              // wave-broadcast (2 addrs)
            float4 w = *(const float4*)(&Wl[k][col4]);  // ds_read_b128
            acc.x += xr * w.x; acc.y += xr * w.y;
            acc.z += xr * w.z; acc.w += xr * w.w;
        }
        int row = row0 + row_in;
        if (row < n) *(float4*)(qkvs + (size_t)row * 128 + col4) = acc;
        __syncthreads();
    }
}

// ================= conv2 projection (32 -> 4x16) ==========================
// qkvs2 layout per node: [0:16)=q, [16:32)=k, [32:48)=v, [48:64)=s
__global__ __launch_bounds__(256) void proj2_kernel(
    const float* __restrict__ h1,
    const float* __restrict__ Wq, const float* __restrict__ bq,
    const float* __restrict__ Wk, const float* __restrict__ bk,
    const float* __restrict__ Wv, const float* __restrict__ bv,
    const float* __restrict__ Ws, const float* __restrict__ bs,
    float* __restrict__ qkvs2, int n)
{
    __shared__ float Wl[32][64];
    __shared__ float bl[64];
    __shared__ float xl[4][32];
    for (int i = threadIdx.x; i < 32 * 64; i += 256) {
        int k = i >> 6, c = i & 63;
        int sub = c >> 4, j = c & 15;
        const float* W = (sub == 0) ? Wq : (sub == 1) ? Wk : (sub == 2) ? Wv : Ws;
        Wl[k][c] = W[k * 16 + j];
    }
    if (threadIdx.x < 64) {
        int c = threadIdx.x, sub = c >> 4, j = c & 15;
        const float* b = (sub == 0) ? bq : (sub == 1) ? bk : (sub == 2) ? bv : bs;
        bl[c] = b[j];
    }
    __syncthreads();
    int r = threadIdx.x >> 6, col = threadIdx.x & 63;
    for (int row0 = blockIdx.x * 4; row0 < n; row0 += gridDim.x * 4) {
        int li = threadIdx.x;
        if (li < 128) {
            int rr = row0 + (li >> 5);
            if (rr < n) xl[li >> 5][li & 31] = h1[(size_t)rr * 32 + (li & 31)];
        }
        __syncthreads();
        int row = row0 + r;
        if (row < n) {
            float acc = bl[col];
            #pragma unroll
            for (int k = 0; k < 32; ++k) acc += xl[r][k] * Wl[k][col];
            qkvs2[(size_t)row * 64 + col] = acc;
        }
        __syncthreads();
    }
}

// ===== conv1 fused gather: online softmax over incoming edges, no atomics =
__global__ __launch_bounds__(256) void gather_conv1(
    const int* __restrict__ row_ptr, const int* __restrict__ deg,
    const int* __restrict__ col, const float* __restrict__ qkvs,
    float* __restrict__ h1, int n)
{
    int tid = blockIdx.x * 256 + threadIdx.x;
    if (tid >= n * HEADS) return;
    int node = tid >> 2, h = tid & 3;
    const float4* qp = (const float4*)(qkvs + (size_t)node * 128 + h * 8);
    float4 q0 = qp[0], q1 = qp[1];
    int start = row_ptr[node], d = deg[node];
    float m = -INFINITY, s = 0.f;
    float a0x=0,a0y=0,a0z=0,a0w=0,a1x=0,a1y=0,a1z=0,a1w=0;
    for (int i = 0; i < d; ++i) {
        int src = col[start + i];
        const float4* kp = (const float4*)(qkvs + (size_t)src * 128 + 32 + h * 8);
        float4 k0 = kp[0], k1 = kp[1];
        float a = (q0.x*k0.x + q0.y*k0.y + q0.z*k0.z + q0.w*k0.w
                 + q1.x*k1.x + q1.y*k1.y + q1.z*k1.z + q1.w*k1.w)
                * 0.35355339059327373f;  // 1/sqrt(8)
        float mn = fmaxf(m, a);
        float corr = __expf(m - mn);   // first iter: exp(-inf)=0
        float ea = __expf(a - mn);
        s = s * corr + ea;
        const float4* vp = (const float4*)(qkvs + (size_t)src * 128 + 64 + h * 8);
        float4 v0 = vp[0], v1 = vp[1];
        a0x = a0x*corr + ea*v0.x; a0y = a0y*corr + ea*v0.y;
        a0z = a0z*corr + ea*v0.z; a0w = a0w*corr + ea*v0.w;
        a1x = a1x*corr + ea*v1.x; a1y = a1y*corr + ea*v1.y;
        a1z = a1z*corr + ea*v1.z; a1w = a1w*corr + ea*v1.w;
        m = mn;
    }
    float inv = 1.f / (s + EPS);
    const float* sk = qkvs + (size_t)node * 128 + 96 + h * 8;
    float4 o0, o1;
    o0.x = fmaxf(a0x*inv + sk[0], 0.f); o0.y = fmaxf(a0y*inv + sk[1], 0.f);
    o0.z = fmaxf(a0z*inv + sk[2], 0.f); o0.w = fmaxf(a0w*inv + sk[3], 0.f);
    o1.x = fmaxf(a1x*inv + sk[4], 0.f); o1.y = fmaxf(a1y*inv + sk[5], 0.f);
    o1.z = fmaxf(a1z*inv + sk[6], 0.f); o1.w = fmaxf(a1w*inv + sk[7], 0.f);
    float4* op = (float4*)(h1 + (size_t)node * 32 + h * 8);
    op[0] = o0; op[1] = o1;
}

// ===== conv2 fused gather (C=4) + skip + relu -> h2[N][16] ================
__global__ __launch_bounds__(256) void gather_conv2(
    const int* __restrict__ row_ptr, const int* __restrict__ deg,
    const int* __restrict__ col, const float* __restrict__ qkvs2,
    float* __restrict__ h2, int n)
{
    int tid = blockIdx.x * 256 + threadIdx.x;
    if (tid >= n * HEADS) return;
    int node = tid >> 2, h = tid & 3;
    float4 q = *(const float4*)(qkvs2 + (size_t)node * 64 + h * 4);
    int start = row_ptr[node], d = deg[node];
    float m = -INFINITY, s = 0.f;
    float ax=0, ay=0, az=0, aw=0;
    for (int i = 0; i < d; ++i) {
        int src = col[start + i];
        float4 k = *(const float4*)(qkvs2 + (size_t)src * 64 + 16 + h * 4);
        float a = (q.x*k.x + q.y*k.y + q.z*k.z + q.w*k.w) * 0.5f; // 1/sqrt(4)
        float mn = fmaxf(m, a);
        float corr = __expf(m - mn);
        float ea = __expf(a - mn);
        s = s * corr + ea;
        float4 v = *(const float4*)(qkvs2 + (size_t)src * 64 + 32 + h * 4);
        ax = ax*corr + ea*v.x; ay = ay*corr + ea*v.y;
        az = az*corr + ea*v.z; aw = aw*corr + ea*v.w;
        m = mn;
    }
    float inv = 1.f / (s + EPS);
    const float* sk = qkvs2 + (size_t)node * 64 + 48 + h * 4;
    float4 o;
    o.x = fmaxf(ax*inv + sk[0], 0.f);
    o.y = fmaxf(ay*inv + sk[1], 0.f);
    o.z = fmaxf(az*inv + sk[2], 0.f);
    o.w = fmaxf(aw*inv + sk[3], 0.f);
    *(float4*)(h2 + (size_t)node * 16 + h * 4) = o;
}

// ====== mean-pool accumulation over h2 (block-local reduce, batch sorted) =
__global__ __launch_bounds__(256) void pool_kernel(
    const float* __restrict__ h2, const int* __restrict__ batch,
    float* __restrict__ pooled, float* __restrict__ cnt, int n)
{
    __shared__ float acc[16];
    __shared__ int bShared;
    __shared__ int uniform;
    int node0 = blockIdx.x * 16;
    int t = threadIdx.x;
    int node = node0 + (t >> 4), j = t & 15;
    if (t == 0) {
        int bFirst = batch[node0];
        int bLast = batch[min(node0 + 15, n - 1)];
        bShared = bFirst;
        uniform = (bFirst == bLast);
    }
    if (t < 16) acc[t] = 0.f;
    __syncthreads();
    bool active = node < n;
    float val = active ? h2[(size_t)node * 16 + j] : 0.f;
    if (uniform) {
        if (active) atomicAdd(&acc[j], val);
        __syncthreads();
        int nlocal = min(16, n - node0);
        if (t < 16) atomicAdd(pooled + bShared * 16 + t, acc[t]);
        if (t == 0) atomicAdd(cnt + bShared, (float)nlocal);
    } else {
        if (active) {
            int b = batch[node];
            atomicAdd(pooled + b * 16 + j, val);
            if (j == 0) atomicAdd(cnt + b, 1.f);
        }
    }
}

// ================= final FC on pooled [64,16] -> [64,10] ==================
__global__ void fc_kernel(
    const float* __restrict__ pooled, const float* __restrict__ cnt,
    const float* __restrict__ Wfc, const float* __restrict__ bfc,
    float* __restrict__ out)
{
    int t = threadIdx.x;
    if (t < 64 * 10) {
        int b = t / 10, o = t % 10;
        float c = fmaxf(cnt[b], 1.0f);
        float acc = bfc[o];
        #pragma unroll
        for (int k = 0; k < 16; ++k)
            acc += (pooled[b * 16 + k] / c) * Wfc[k * 10 + o];
        out[t] = acc;
    }
}

extern "C" void kernel_launch(void* const* d_in, const int* in_sizes, int n_in,
                              void* d_out, int out_size, void* d_ws, size_t ws_size,
                              hipStream_t stream) {
    const float* x     = (const float*)d_in[0];
    const int*   ei    = (const int*)d_in[1];
    const int*   batch = (const int*)d_in[2];
    const float* Wq1 = (const float*)d_in[3],  *bq1 = (const float*)d_in[4];
    const float* Wk1 = (const float*)d_in[5],  *bk1 = (const float*)d_in[6];
    const float* Wv1 = (const float*)d_in[7],  *bv1 = (const float*)d_in[8];
    const float* Ws1 = (const float*)d_in[9],  *bs1 = (const float*)d_in[10];
    const float* Wq2 = (const float*)d_in[11], *bq2 = (const float*)d_in[12];
    const float* Wk2 = (const float*)d_in[13], *bk2 = (const float*)d_in[14];
    const float* Wv2 = (const float*)d_in[15], *bv2 = (const float*)d_in[16];
    const float* Ws2 = (const float*)d_in[17], *bs2 = (const float*)d_in[18];
    const float* Wfc = (const float*)d_in[19], *bfc = (const float*)d_in[20];

    int N = in_sizes[0] / 128;
    int E = in_sizes[1] / 2;

    // ---- workspace layout ----
    float* ws = (float*)d_ws;
    float* qkvs1  = ws;                                   // N*128 f (conv2 reuses as qkvs2: N*64)
    float* h1     = qkvs1 + (size_t)N * 128;              // N*32 f (aliased as rank[] during CSR build)
    float* h2     = h1 + (size_t)N * 32;                  // N*16 f
    float* pooled = h2 + (size_t)N * 16;                  // 64*16 f
    float* cnt    = pooled + 64 * 16;                     // 64 f
    int* deg     = (int*)(cnt + 64);                      // N ints
    int* row_ptr = deg + N;                               // N ints
    int* bsum    = row_ptr + N;                           // SB ints
    int* col     = bsum + SB;                             // E ints
    int* rank    = (int*)h1;                              // E ints, dead after fill_kernel

    // zero: deg (histogram) + pooled + cnt (accumulators). every call.
    hipMemsetAsync(deg, 0, (size_t)N * sizeof(int), stream);
    hipMemsetAsync(pooled, 0, (64 * 16 + 64) * sizeof(float), stream);

    int ngrid = (N * HEADS + 255) / 256;

    // ---- CSR build (shared by both convs) ----
    degree_rank_kernel<<<(E + 1023) / 1024, 256, 0, stream>>>(ei, E, deg, rank);
    scan_partial<<<SB, 256, 0, stream>>>(deg, bsum, N);
    scan_bsums<<<1, 256, 0, stream>>>(bsum);
    scan_write<<<SB, 256, 0, stream>>>(deg, bsum, row_ptr, N);
    fill_kernel<<<2048, 256, 0, stream>>>(ei, rank, row_ptr, E, N, col);

    // ---- conv1 ----
    proj1_kernel<<<1024, 256, 0, stream>>>(x, Wq1, bq1, Wk1, bk1, Wv1, bv1, Ws1, bs1, qkvs1, N);
    gather_conv1<<<ngrid, 256, 0, stream>>>(row_ptr, deg, col, qkvs1, h1, N);

    // ---- conv2 (qkvs2 reuses qkvs1 region) ----
    proj2_kernel<<<1024, 256, 0, stream>>>(h1, Wq2, bq2, Wk2, bk2, Wv2, bv2, Ws2, bs2, qkvs1, N);
    gather_conv2<<<ngrid, 256, 0, stream>>>(row_ptr, deg, col, qkvs1, h2, N);

    // ---- pool + fc ----
    pool_kernel<<<(N + 15) / 16, 256, 0, stream>>>(h2, batch, pooled, cnt, N);
    fc_kernel<<<1, 640, 0, stream>>>(pooled, cnt, Wfc, bfc, (float*)d_out);
}

// Round 5
// 521.189 us; speedup vs baseline: 8.0260x; 1.2948x over previous
//
#include <hip/hip_runtime.h>

#define HEADS 4
#define EPS 1e-16f
#define SB 256   // scan blocks

// bf16 helpers (RNE pack, cheap unpack via bit shifts)
__device__ inline unsigned short f2bf(float f) {
    union { float f; unsigned u; } v; v.f = f;
    unsigned r = v.u + 0x7FFFu + ((v.u >> 16) & 1u);
    return (unsigned short)(r >> 16);
}
#define BLO(u) __uint_as_float((u) << 16)
#define BHI(u) __uint_as_float((u) & 0xFFFF0000u)

// ========== CSR pass 1: degree histogram + per-edge rank (atomic return) ==
__global__ __launch_bounds__(256) void degree_rank_kernel(
    const int* __restrict__ ei, int E, int* __restrict__ deg,
    int* __restrict__ rank)
{
    int base = (blockIdx.x * 256 + threadIdx.x) * 4;
    if (base + 3 < E) {
        int4 d = *(const int4*)(ei + E + base);
        int r0 = atomicAdd(deg + d.x, 1);
        int r1 = atomicAdd(deg + d.y, 1);
        int r2 = atomicAdd(deg + d.z, 1);
        int r3 = atomicAdd(deg + d.w, 1);
        *(int4*)(rank + base) = make_int4(r0, r1, r2, r3);
    } else {
        for (int e = base; e < E; ++e)
            rank[e] = atomicAdd(deg + ei[E + e], 1);
    }
}

// ============ CSR pass 2a: per-block partial sums of deg ==================
__global__ __launch_bounds__(256) void scan_partial(
    const int* __restrict__ deg, int* __restrict__ bsum, int n)
{
    __shared__ int red[256];
    int chunk = (n + SB - 1) / SB;
    int lo = blockIdx.x * chunk;
    int hi = min(lo + chunk, n);
    int s = 0;
    for (int i = lo + threadIdx.x; i < hi; i += 256) s += deg[i];
    red[threadIdx.x] = s;
    __syncthreads();
    for (int off = 128; off > 0; off >>= 1) {
        if (threadIdx.x < off) red[threadIdx.x] += red[threadIdx.x + off];
        __syncthreads();
    }
    if (threadIdx.x == 0) bsum[blockIdx.x] = red[0];
}

// ============ CSR pass 2b: exclusive scan of the 256 block sums ===========
__global__ __launch_bounds__(256) void scan_bsums(int* __restrict__ bsum)
{
    __shared__ int tmp[256];
    int t = threadIdx.x;
    tmp[t] = bsum[t];
    __syncthreads();
    for (int off = 1; off < 256; off <<= 1) {
        int add = (t >= off) ? tmp[t - off] : 0;
        __syncthreads();
        tmp[t] += add;
        __syncthreads();
    }
    bsum[t] = (t == 0) ? 0 : tmp[t - 1];
}

// ============ CSR pass 2c: per-block exclusive scan -> row_ptr ============
__global__ __launch_bounds__(256) void scan_write(
    const int* __restrict__ deg, const int* __restrict__ bsum,
    int* __restrict__ row_ptr, int n)
{
    __shared__ int tmp[256];
    int chunk = (n + SB - 1) / SB;
    int lo = blockIdx.x * chunk;
    int hi = min(lo + chunk, n);
    int k = (chunk + 255) / 256;
    int tlo = lo + threadIdx.x * k;
    int thi = min(tlo + k, hi);
    int s = 0;
    for (int i = tlo; i < thi; ++i) s += deg[i];
    tmp[threadIdx.x] = s;
    __syncthreads();
    for (int off = 1; off < 256; off <<= 1) {
        int add = (threadIdx.x >= off) ? tmp[threadIdx.x - off] : 0;
        __syncthreads();
        tmp[threadIdx.x] += add;
        __syncthreads();
    }
    int prefix = bsum[blockIdx.x] + ((threadIdx.x == 0) ? 0 : tmp[threadIdx.x - 1]);
    for (int i = tlo; i < thi; ++i) {
        row_ptr[i] = prefix;
        prefix += deg[i];
    }
}

// ==== CSR pass 3: XCD-partitioned fill, no atomics, write-local col =======
__global__ __launch_bounds__(256) void fill_kernel(
    const int* __restrict__ ei, const int* __restrict__ rank,
    const int* __restrict__ row_ptr, int E, int n, int* __restrict__ col)
{
    int part = blockIdx.x & 7;
    int g = blockIdx.x >> 3;
    int nb = gridDim.x >> 3;
    int lo = (int)(((long long)n * part) >> 3);
    int hi = (int)(((long long)n * (part + 1)) >> 3);
    int stride = nb * 256 * 4;
    for (int base = (g * 256 + threadIdx.x) * 4; base < E; base += stride) {
        if (base + 3 < E) {
            int4 d = *(const int4*)(ei + E + base);
            if (d.x >= lo && d.x < hi) col[row_ptr[d.x] + rank[base + 0]] = ei[base + 0];
            if (d.y >= lo && d.y < hi) col[row_ptr[d.y] + rank[base + 1]] = ei[base + 1];
            if (d.z >= lo && d.z < hi) col[row_ptr[d.z] + rank[base + 2]] = ei[base + 2];
            if (d.w >= lo && d.w < hi) col[row_ptr[d.w] + rank[base + 3]] = ei[base + 3];
        } else {
            for (int e = base; e < E; ++e) {
                int dv = ei[E + e];
                if (dv >= lo && dv < hi) col[row_ptr[dv] + rank[e]] = ei[e];
            }
        }
    }
}

// ================= conv1: fused QKVS projection (128 -> 4x32) =============
// Outputs split: qs1[N][64] fp32 (q|s), kv1[N][64] bf16 (k|v, one 128B line)
__global__ __launch_bounds__(256) void proj1_kernel(
    const float* __restrict__ x,
    const float* __restrict__ Wq, const float* __restrict__ bq,
    const float* __restrict__ Wk, const float* __restrict__ bk,
    const float* __restrict__ Wv, const float* __restrict__ bv,
    const float* __restrict__ Ws, const float* __restrict__ bs,
    float* __restrict__ qs1, unsigned short* __restrict__ kv1, int n)
{
    __shared__ float Wl[128][128];
    __shared__ float xl[8][128];
    for (int i = threadIdx.x; i < 128 * 128; i += 256) {
        int k = i >> 7, c = i & 127;
        int sub = c >> 5, j = c & 31;
        const float* W = (sub == 0) ? Wq : (sub == 1) ? Wk : (sub == 2) ? Wv : Ws;
        Wl[k][c] = W[k * 32 + j];
    }
    int col4 = (threadIdx.x & 31) * 4;
    int sub = col4 >> 5, j = col4 & 31;
    float4 bias4;
    {
        const float* b = (sub == 0) ? bq : (sub == 1) ? bk : (sub == 2) ? bv : bs;
        bias4 = *(const float4*)(b + j);
    }
    __syncthreads();
    int row_in = threadIdx.x >> 5;   // 0..7
    for (int row0 = blockIdx.x * 8; row0 < n; row0 += gridDim.x * 8) {
        int f4 = threadIdx.x;
        int gr = row0 + (f4 >> 5);
        float4 xv = (gr < n) ? *(const float4*)(x + (size_t)gr * 128 + (f4 & 31) * 4)
                             : make_float4(0.f, 0.f, 0.f, 0.f);
        *(float4*)(&xl[f4 >> 5][(f4 & 31) * 4]) = xv;
        __syncthreads();
        float4 acc = bias4;
        #pragma unroll 8
        for (int k = 0; k < 128; ++k) {
            float xr = xl[row_in][k];
            float4 w = *(const float4*)(&Wl[k][col4]);
            acc.x += xr * w.x; acc.y += xr * w.y;
            acc.z += xr * w.z; acc.w += xr * w.w;
        }
        int row = row0 + row_in;
        if (row < n) {
            if (sub == 0)
                *(float4*)(qs1 + (size_t)row * 64 + j) = acc;
            else if (sub == 3)
                *(float4*)(qs1 + (size_t)row * 64 + 32 + j) = acc;
            else {
                ushort4 p = make_ushort4(f2bf(acc.x), f2bf(acc.y), f2bf(acc.z), f2bf(acc.w));
                *(ushort4*)(kv1 + (size_t)row * 64 + ((sub == 1) ? 0 : 32) + j) = p;
            }
        }
        __syncthreads();
    }
}

// ================= conv2 projection (32 -> 4x16) ==========================
// Outputs split: qs2[N][32] fp32 (q|s), kv2[N][32] bf16 (k|v, 64B)
__global__ __launch_bounds__(256) void proj2_kernel(
    const float* __restrict__ h1,
    const float* __restrict__ Wq, const float* __restrict__ bq,
    const float* __restrict__ Wk, const float* __restrict__ bk,
    const float* __restrict__ Wv, const float* __restrict__ bv,
    const float* __restrict__ Ws, const float* __restrict__ bs,
    float* __restrict__ qs2, unsigned short* __restrict__ kv2, int n)
{
    __shared__ float Wl[32][64];
    __shared__ float bl[64];
    __shared__ float xl[4][32];
    for (int i = threadIdx.x; i < 32 * 64; i += 256) {
        int k = i >> 6, c = i & 63;
        int sub = c >> 4, j = c & 15;
        const float* W = (sub == 0) ? Wq : (sub == 1) ? Wk : (sub == 2) ? Wv : Ws;
        Wl[k][c] = W[k * 16 + j];
    }
    if (threadIdx.x < 64) {
        int c = threadIdx.x, sub = c >> 4, j = c & 15;
        const float* b = (sub == 0) ? bq : (sub == 1) ? bk : (sub == 2) ? bv : bs;
        bl[c] = b[j];
    }
    __syncthreads();
    int r = threadIdx.x >> 6, col = threadIdx.x & 63;
    int sub = col >> 4, j = col & 15;
    for (int row0 = blockIdx.x * 4; row0 < n; row0 += gridDim.x * 4) {
        int li = threadIdx.x;
        if (li < 128) {
            int rr = row0 + (li >> 5);
            if (rr < n) xl[li >> 5][li & 31] = h1[(size_t)rr * 32 + (li & 31)];
        }
        __syncthreads();
        int row = row0 + r;
        if (row < n) {
            float acc = bl[col];
            #pragma unroll
            for (int k = 0; k < 32; ++k) acc += xl[r][k] * Wl[k][col];
            if (sub == 0)       qs2[(size_t)row * 32 + j] = acc;
            else if (sub == 3)  qs2[(size_t)row * 32 + 16 + j] = acc;
            else                kv2[(size_t)row * 32 + ((sub == 1) ? 0 : 16) + j] = f2bf(acc);
        }
        __syncthreads();
    }
}

// ===== conv1 fused gather: online softmax, bf16 KV, 1-deep SW pipeline ====
__global__ __launch_bounds__(256) void gather_conv1(
    const int* __restrict__ row_ptr, const int* __restrict__ deg,
    const int* __restrict__ col, const float* __restrict__ qs1,
    const unsigned short* __restrict__ kv1, float* __restrict__ h1, int n)
{
    int tid = blockIdx.x * 256 + threadIdx.x;
    if (tid >= n * HEADS) return;
    int node = tid >> 2, h = tid & 3;
    const float4* qp = (const float4*)(qs1 + (size_t)node * 64 + h * 8);
    float4 q0 = qp[0], q1 = qp[1];
    int start = row_ptr[node], d = deg[node];
    float m = -INFINITY, s = 0.f;
    float a0x=0,a0y=0,a0z=0,a0w=0,a1x=0,a1y=0,a1z=0,a1w=0;
    uint4 ku = make_uint4(0,0,0,0), vu = make_uint4(0,0,0,0);
    if (d > 0) {
        const unsigned short* b0 = kv1 + (size_t)col[start] * 64;
        ku = *(const uint4*)(b0 + h * 8);
        vu = *(const uint4*)(b0 + 32 + h * 8);
    }
    for (int i = 0; i < d; ++i) {
        uint4 kn = ku, vn = vu;
        if (i + 1 < d) {
            const unsigned short* nb = kv1 + (size_t)col[start + i + 1] * 64;
            kn = *(const uint4*)(nb + h * 8);
            vn = *(const uint4*)(nb + 32 + h * 8);
        }
        float a = (q0.x*BLO(ku.x) + q0.y*BHI(ku.x)
                 + q0.z*BLO(ku.y) + q0.w*BHI(ku.y)
                 + q1.x*BLO(ku.z) + q1.y*BHI(ku.z)
                 + q1.z*BLO(ku.w) + q1.w*BHI(ku.w))
                * 0.35355339059327373f;  // 1/sqrt(8)
        float mn = fmaxf(m, a);
        float corr = __expf(m - mn);   // first iter: exp(-inf)=0
        float ea = __expf(a - mn);
        s = s * corr + ea;
        a0x = a0x*corr + ea*BLO(vu.x); a0y = a0y*corr + ea*BHI(vu.x);
        a0z = a0z*corr + ea*BLO(vu.y); a0w = a0w*corr + ea*BHI(vu.y);
        a1x = a1x*corr + ea*BLO(vu.z); a1y = a1y*corr + ea*BHI(vu.z);
        a1z = a1z*corr + ea*BLO(vu.w); a1w = a1w*corr + ea*BHI(vu.w);
        m = mn;
        ku = kn; vu = vn;
    }
    float inv = 1.f / (s + EPS);
    const float* sk = qs1 + (size_t)node * 64 + 32 + h * 8;
    float4 o0, o1;
    o0.x = fmaxf(a0x*inv + sk[0], 0.f); o0.y = fmaxf(a0y*inv + sk[1], 0.f);
    o0.z = fmaxf(a0z*inv + sk[2], 0.f); o0.w = fmaxf(a0w*inv + sk[3], 0.f);
    o1.x = fmaxf(a1x*inv + sk[4], 0.f); o1.y = fmaxf(a1y*inv + sk[5], 0.f);
    o1.z = fmaxf(a1z*inv + sk[6], 0.f); o1.w = fmaxf(a1w*inv + sk[7], 0.f);
    float4* op = (float4*)(h1 + (size_t)node * 32 + h * 8);
    op[0] = o0; op[1] = o1;
}

// ===== conv2 fused gather (C=4), bf16 KV, 1-deep SW pipeline ==============
__global__ __launch_bounds__(256) void gather_conv2(
    const int* __restrict__ row_ptr, const int* __restrict__ deg,
    const int* __restrict__ col, const float* __restrict__ qs2,
    const unsigned short* __restrict__ kv2, float* __restrict__ h2, int n)
{
    int tid = blockIdx.x * 256 + threadIdx.x;
    if (tid >= n * HEADS) return;
    int node = tid >> 2, h = tid & 3;
    float4 q = *(const float4*)(qs2 + (size_t)node * 32 + h * 4);
    int start = row_ptr[node], d = deg[node];
    float m = -INFINITY, s = 0.f;
    float ax=0, ay=0, az=0, aw=0;
    uint2 ku = make_uint2(0,0), vu = make_uint2(0,0);
    if (d > 0) {
        const unsigned short* b0 = kv2 + (size_t)col[start] * 32;
        ku = *(const uint2*)(b0 + h * 4);
        vu = *(const uint2*)(b0 + 16 + h * 4);
    }
    for (int i = 0; i < d; ++i) {
        uint2 kn = ku, vn = vu;
        if (i + 1 < d) {
            const unsigned short* nb = kv2 + (size_t)col[start + i + 1] * 32;
            kn = *(const uint2*)(nb + h * 4);
            vn = *(const uint2*)(nb + 16 + h * 4);
        }
        float a = (q.x*BLO(ku.x) + q.y*BHI(ku.x)
                 + q.z*BLO(ku.y) + q.w*BHI(ku.y)) * 0.5f; // 1/sqrt(4)
        float mn = fmaxf(m, a);
        float corr = __expf(m - mn);
        float ea = __expf(a - mn);
        s = s * corr + ea;
        ax = ax*corr + ea*BLO(vu.x); ay = ay*corr + ea*BHI(vu.x);
        az = az*corr + ea*BLO(vu.y); aw = aw*corr + ea*BHI(vu.y);
        m = mn;
        ku = kn; vu = vn;
    }
    float inv = 1.f / (s + EPS);
    const float* sk = qs2 + (size_t)node * 32 + 16 + h * 4;
    float4 o;
    o.x = fmaxf(ax*inv + sk[0], 0.f);
    o.y = fmaxf(ay*inv + sk[1], 0.f);
    o.z = fmaxf(az*inv + sk[2], 0.f);
    o.w = fmaxf(aw*inv + sk[3], 0.f);
    *(float4*)(h2 + (size_t)node * 16 + h * 4) = o;
}

// ====== mean-pool accumulation over h2 (block-local reduce, batch sorted) =
__global__ __launch_bounds__(256) void pool_kernel(
    const float* __restrict__ h2, const int* __restrict__ batch,
    float* __restrict__ pooled, float* __restrict__ cnt, int n)
{
    __shared__ float acc[16];
    __shared__ int bShared;
    __shared__ int uniform;
    int node0 = blockIdx.x * 16;
    int t = threadIdx.x;
    int node = node0 + (t >> 4), j = t & 15;
    if (t == 0) {
        int bFirst = batch[node0];
        int bLast = batch[min(node0 + 15, n - 1)];
        bShared = bFirst;
        uniform = (bFirst == bLast);
    }
    if (t < 16) acc[t] = 0.f;
    __syncthreads();
    bool active = node < n;
    float val = active ? h2[(size_t)node * 16 + j] : 0.f;
    if (uniform) {
        if (active) atomicAdd(&acc[j], val);
        __syncthreads();
        int nlocal = min(16, n - node0);
        if (t < 16) atomicAdd(pooled + bShared * 16 + t, acc[t]);
        if (t == 0) atomicAdd(cnt + bShared, (float)nlocal);
    } else {
        if (active) {
            int b = batch[node];
            atomicAdd(pooled + b * 16 + j, val);
            if (j == 0) atomicAdd(cnt + b, 1.f);
        }
    }
}

// ================= final FC on pooled [64,16] -> [64,10] ==================
__global__ void fc_kernel(
    const float* __restrict__ pooled, const float* __restrict__ cnt,
    const float* __restrict__ Wfc, const float* __restrict__ bfc,
    float* __restrict__ out)
{
    int t = threadIdx.x;
    if (t < 64 * 10) {
        int b = t / 10, o = t % 10;
        float c = fmaxf(cnt[b], 1.0f);
        float acc = bfc[o];
        #pragma unroll
        for (int k = 0; k < 16; ++k)
            acc += (pooled[b * 16 + k] / c) * Wfc[k * 10 + o];
        out[t] = acc;
    }
}

extern "C" void kernel_launch(void* const* d_in, const int* in_sizes, int n_in,
                              void* d_out, int out_size, void* d_ws, size_t ws_size,
                              hipStream_t stream) {
    const float* x     = (const float*)d_in[0];
    const int*   ei    = (const int*)d_in[1];
    const int*   batch = (const int*)d_in[2];
    const float* Wq1 = (const float*)d_in[3],  *bq1 = (const float*)d_in[4];
    const float* Wk1 = (const float*)d_in[5],  *bk1 = (const float*)d_in[6];
    const float* Wv1 = (const float*)d_in[7],  *bv1 = (const float*)d_in[8];
    const float* Ws1 = (const float*)d_in[9],  *bs1 = (const float*)d_in[10];
    const float* Wq2 = (const float*)d_in[11], *bq2 = (const float*)d_in[12];
    const float* Wk2 = (const float*)d_in[13], *bk2 = (const float*)d_in[14];
    const float* Wv2 = (const float*)d_in[15], *bv2 = (const float*)d_in[16];
    const float* Ws2 = (const float*)d_in[17], *bs2 = (const float*)d_in[18];
    const float* Wfc = (const float*)d_in[19], *bfc = (const float*)d_in[20];

    int N = in_sizes[0] / 128;
    int E = in_sizes[1] / 2;

    // ---- workspace layout (all offsets keep kv1 128B-aligned) ----
    float* ws = (float*)d_ws;
    float* qs1    = ws;                                   // N*64 f  (q|s conv1)
    float* h1     = qs1 + (size_t)N * 64;                 // N*32 f  (rank aliases)
    float* h2     = h1 + (size_t)N * 32;                  // N*16 f
    float* qs2    = h2 + (size_t)N * 16;                  // N*32 f  (q|s conv2)
    float* pooled = qs2 + (size_t)N * 32;                 // 1024 f
    float* cnt    = pooled + 1024;                        // 64 f
    unsigned short* kv1 = (unsigned short*)(cnt + 64);    // N*64 bf16 (128B/node)
    unsigned short* kv2 = kv1 + (size_t)N * 64;           // N*32 bf16 (64B/node)
    int* deg     = (int*)(kv2 + (size_t)N * 32);          // N ints
    int* row_ptr = deg + N;                               // N ints
    int* bsum    = row_ptr + N;                           // SB ints
    int* col     = bsum + SB;                             // E ints
    int* rank    = (int*)h1;                              // E ints, dead after fill

    // zero: deg (histogram) + pooled + cnt (accumulators). every call.
    hipMemsetAsync(deg, 0, (size_t)N * sizeof(int), stream);
    hipMemsetAsync(pooled, 0, (64 * 16 + 64) * sizeof(float), stream);

    int ngrid = (N * HEADS + 255) / 256;

    // ---- CSR build (shared by both convs) ----
    degree_rank_kernel<<<(E + 1023) / 1024, 256, 0, stream>>>(ei, E, deg, rank);
    scan_partial<<<SB, 256, 0, stream>>>(deg, bsum, N);
    scan_bsums<<<1, 256, 0, stream>>>(bsum);
    scan_write<<<SB, 256, 0, stream>>>(deg, bsum, row_ptr, N);
    fill_kernel<<<2048, 256, 0, stream>>>(ei, rank, row_ptr, E, N, col);

    // ---- conv1 ----
    proj1_kernel<<<1024, 256, 0, stream>>>(x, Wq1, bq1, Wk1, bk1, Wv1, bv1, Ws1, bs1, qs1, kv1, N);
    gather_conv1<<<ngrid, 256, 0, stream>>>(row_ptr, deg, col, qs1, kv1, h1, N);

    // ---- conv2 ----
    proj2_kernel<<<1024, 256, 0, stream>>>(h1, Wq2, bq2, Wk2, bk2, Wv2, bv2, Ws2, bs2, qs2, kv2, N);
    gather_conv2<<<ngrid, 256, 0, stream>>>(row_ptr, deg, col, qs2, kv2, h2, N);

    // ---- pool + fc ----
    pool_kernel<<<(N + 15) / 16, 256, 0, stream>>>(h2, batch, pooled, cnt, N);
    fc_kernel<<<1, 640, 0, stream>>>(pooled, cnt, Wfc, bfc, (float*)d_out);
}